// Round 7
// baseline (158.065 us; speedup 1.0000x reference)
//
#include <hip/hip_runtime.h>
#include <hip/hip_bf16.h>
#include <type_traits>

typedef __attribute__((ext_vector_type(8))) short bf16x8;
typedef __attribute__((ext_vector_type(4))) float f32x4;
typedef __attribute__((ext_vector_type(4))) int   i32x4;

static __device__ __forceinline__ unsigned short f2bf(float f) {
  union { float f; unsigned u; } cv; cv.f = f;
  unsigned r = cv.u + 0x7fff + ((cv.u >> 16) & 1);   // RNE, no NaNs in this data
  return (unsigned short)(r >> 16);
}

static __device__ __forceinline__ void stage16(const void* g, void* l) {
  __builtin_amdgcn_global_load_lds((const __attribute__((address_space(1))) void*)g,
                                   (__attribute__((address_space(3))) void*)l,
                                   16, 0, 0);
}

// ---------------- prep ----------------
// y==0 (1024 blocks): x f32 -> int8. y==1/2 (96 blocks): maxabs(w1/w2).
__global__ void prep_kernel(const float4* __restrict__ x, uchar4* __restrict__ xq, int n4x,
                            const float4* __restrict__ w1, const float4* __restrict__ w2,
                            int n4w, unsigned* __restrict__ mx) {
  if (blockIdx.y == 0) {
    const int stride = gridDim.x * blockDim.x;
    for (int i = blockIdx.x * blockDim.x + threadIdx.x; i < n4x; i += stride) {
      float4 v = x[i];
      uchar4 o;
      o.x = (unsigned char)(char)fminf(fmaxf(v.x, -127.f), 127.f);
      o.y = (unsigned char)(char)fminf(fmaxf(v.y, -127.f), 127.f);
      o.z = (unsigned char)(char)fminf(fmaxf(v.z, -127.f), 127.f);
      o.w = (unsigned char)(char)fminf(fmaxf(v.w, -127.f), 127.f);
      xq[i] = o;
    }
  } else {
    if (blockIdx.x >= 96) return;
    __shared__ unsigned red[4];
    const float4* w = (blockIdx.y == 1) ? w1 : w2;
    unsigned m = 0;
    const int stride = 96 * 256;
    for (int i = blockIdx.x * blockDim.x + threadIdx.x; i < n4w; i += stride) {
      float4 v = w[i];
      unsigned a;
      a = __float_as_uint(fabsf(v.x)); m = m > a ? m : a;
      a = __float_as_uint(fabsf(v.y)); m = m > a ? m : a;
      a = __float_as_uint(fabsf(v.z)); m = m > a ? m : a;
      a = __float_as_uint(fabsf(v.w)); m = m > a ? m : a;
    }
#pragma unroll
    for (int off = 32; off > 0; off >>= 1) {
      unsigned t = (unsigned)__shfl_down((int)m, off, 64);
      m = m > t ? m : t;
    }
    if ((threadIdx.x & 63) == 0) red[threadIdx.x >> 6] = m;
    __syncthreads();
    if (threadIdx.x == 0) {
      unsigned t0 = red[0] > red[1] ? red[0] : red[1];
      unsigned t1 = red[2] > red[3] ? red[2] : red[3];
      atomicMax(mx + blockIdx.y - 1, t0 > t1 ? t0 : t1);
    }
  }
}

// y==0: w1 -> int8 ; y==1: w2 -> bf16 ; y==2 (block 0): biases + final scale.
// Each block derives scales directly from mx (deterministic).
__global__ void quantwb_kernel(const float4* __restrict__ w1, const float4* __restrict__ w2,
                               uchar4* __restrict__ w1q, ushort4* __restrict__ w2q,
                               const float* __restrict__ b1, const float* __restrict__ b2,
                               float* __restrict__ b1i, float* __restrict__ b2i,
                               const unsigned* __restrict__ mx, const float* __restrict__ a_s,
                               float* __restrict__ s_out, int n4, int H, int D) {
  const float ws1 = __uint_as_float(mx[0]) / 127.0f;
  const float ws2 = __uint_as_float(mx[1]) / 127.0f;
  const int stride = gridDim.x * blockDim.x;
  if (blockIdx.y == 0) {
    for (int i = blockIdx.x * blockDim.x + threadIdx.x; i < n4; i += stride) {
      float4 v = w1[i];
      uchar4 o;
      o.x = (unsigned char)(char)fminf(fmaxf(rintf(v.x / ws1), -127.f), 127.f);
      o.y = (unsigned char)(char)fminf(fmaxf(rintf(v.y / ws1), -127.f), 127.f);
      o.z = (unsigned char)(char)fminf(fmaxf(rintf(v.z / ws1), -127.f), 127.f);
      o.w = (unsigned char)(char)fminf(fmaxf(rintf(v.w / ws1), -127.f), 127.f);
      w1q[i] = o;
    }
  } else if (blockIdx.y == 1) {
    for (int i = blockIdx.x * blockDim.x + threadIdx.x; i < n4; i += stride) {
      float4 v = w2[i];
      ushort4 o;
      o.x = f2bf(fminf(fmaxf(rintf(v.x / ws2), -127.f), 127.f));
      o.y = f2bf(fminf(fmaxf(rintf(v.y / ws2), -127.f), 127.f));
      o.z = f2bf(fminf(fmaxf(rintf(v.z / ws2), -127.f), 127.f));
      o.w = f2bf(fminf(fmaxf(rintf(v.w / ws2), -127.f), 127.f));
      w2q[i] = o;
    }
  } else {
    if (blockIdx.x != 0) return;
    const float s0 = a_s[0];
    const float s1 = s0 * ws1;
    const float d1 = ws1 * s0;
    const float d2 = ws2 * s1;
    if (threadIdx.x == 0) s_out[0] = s1 * ws2;
    for (int i = threadIdx.x; i < H; i += blockDim.x) {
      float q = rintf(b1[i] / d1);
      b1i[i] = fminf(fmaxf(q, -2147483647.f), 2147483647.f);
    }
    for (int i = threadIdx.x; i < D; i += blockDim.x) {
      float q = rintf(b2[i] / d2);
      b2i[i] = fminf(fmaxf(q, -2147483647.f), 2147483647.f);
    }
  }
}

// ---------------- 3-slot no-drain GEMM, 128x128 tile, BK=64 bytes ----------------
// MODE 0 (fc1): int8 (mfma_i32_16x16x64_i8), bf16 out, 16-row-band ordering.
// MODE 1 (fc2): bf16 (mfma_f32_16x16x32_bf16), f32 out + ReLU, row-major + m204.
// LDS = 3 slots x (8KB A + 8KB B) = 48 KB -> 3 blocks/CU. Per step:
//   8 ds_read_b128 -> stage slot (t+2)%3 -> 16 MFMA (compiler lgkm interleave)
//   -> vmcnt(4) [counted, never 0 mid-loop] -> s_barrier.
// No lgkm drain: stage target slot's readers finished before prior barrier
// (MFMA register deps force ds_read completion before barrier arrival).
// Chunk swizzle phys = logical ^ ((row>>1)&3) on global source + ds_read addr:
// uniform 8 lanes per bank-start on b128 reads (optimal), 0 conflicts.

template<int MODE>
static __device__ __forceinline__ void gemm_core(
    char* lds,
    const char* __restrict__ A, const char* __restrict__ Bt,
    const float* __restrict__ bias, void* __restrict__ Cout,
    int M, int N, int Kb)
{
  const int tid = threadIdx.x;
  const int lane = tid & 63;
  const int wave = tid >> 6;
  const int wr = wave >> 1;
  const int wc = wave & 1;

  const int nbx = M / 128;
  const int nby = N / 128;
  int r, c;
  if (MODE == 0) {
    const int bandSize = 16 * nby;
    const int b = blockIdx.x / bandSize;
    const int local = blockIdx.x - b * bandSize;
    const int r0 = b * 16;
    const int rn = min(16, nbx - r0);
    c = local / rn;
    r = r0 + (local - c * rn);
  } else {
    const int nwg = nbx * nby;
    const int q8 = nwg >> 3, r8 = nwg & 7;
    const int xcd = blockIdx.x & 7, bidx = blockIdx.x >> 3;
    const int wg = (xcd < r8 ? xcd * (q8 + 1) : r8 * (q8 + 1) + (xcd - r8) * q8) + bidx;
    r = wg / nby;
    c = wg % nby;
  }
  const int row0 = r * 128;
  const int col0 = c * 128;

  // staging: thread t -> row (t>>2)+64i, phys chunk t&3 (LDS linear t*16B + i*4096)
  const int srow = tid >> 2;
  const int chunk = (tid & 3) ^ ((tid >> 3) & 3);
  const char* Ag = A + (size_t)(row0 + srow) * Kb + chunk * 16;
  const char* Bg = Bt + (size_t)(col0 + srow) * Kb + chunk * 16;
  const int wb = wave * 1024;

  auto stage = [&](int slot, int st) {
    char* base = lds + slot * 16384;
    const int ko = st * 64;
    stage16(Ag + ko, base + wb);
    stage16(Ag + ko + (size_t)64 * Kb, base + 4096 + wb);
    stage16(Bg + ko, base + 8192 + wb);
    stage16(Bg + ko + (size_t)64 * Kb, base + 12288 + wb);
  };

  using accv = typename std::conditional<MODE == 0, i32x4, f32x4>::type;
  using frag = typename std::conditional<MODE == 0, i32x4, bf16x8>::type;
  accv acc[4][4];
#pragma unroll
  for (int i = 0; i < 4; ++i)
#pragma unroll
    for (int j = 0; j < 4; ++j) acc[i][j] = (accv)(0);

  const int nS = Kb >> 6;              // 12 (fc1) / 96 (fc2)
  stage(0, 0);
  stage(1, 1);
  asm volatile("s_waitcnt vmcnt(4)" ::: "memory");
  __builtin_amdgcn_s_barrier();

  const int fr = lane & 15;
  const int fg = lane >> 4;
  const int xw = (fg ^ ((fr >> 1) & 3)) << 4;
  const int aoff = (wr * 64 + fr) * 64 + xw;
  const int boff = 8192 + (wc * 64 + fr) * 64 + xw;

  int rs = 0, ss = 2;
  for (int t = 0; t < nS; ++t) {
    const int so = rs << 14;
    frag af[4], bf[4];
#pragma unroll
    for (int mi = 0; mi < 4; ++mi) af[mi] = *(const frag*)(lds + so + aoff + mi * 1024);
#pragma unroll
    for (int ni = 0; ni < 4; ++ni) bf[ni] = *(const frag*)(lds + so + boff + ni * 1024);
    const bool st = (t + 2 < nS);
    if (st) stage(ss, t + 2);
    __builtin_amdgcn_s_setprio(1);
#pragma unroll
    for (int mi = 0; mi < 4; ++mi)
#pragma unroll
      for (int ni = 0; ni < 4; ++ni) {
        if (MODE == 0)
          acc[mi][ni] = __builtin_amdgcn_mfma_i32_16x16x64_i8(
              (i32x4)af[mi], (i32x4)bf[ni], (i32x4)acc[mi][ni], 0, 0, 0);
        else
          acc[mi][ni] = __builtin_amdgcn_mfma_f32_16x16x32_bf16(
              (bf16x8)af[mi], (bf16x8)bf[ni], (f32x4)acc[mi][ni], 0, 0, 0);
      }
    __builtin_amdgcn_s_setprio(0);
    if (t + 1 < nS) {
      if (st) asm volatile("s_waitcnt vmcnt(4)" ::: "memory");
      else    asm volatile("s_waitcnt vmcnt(0)" ::: "memory");
      __builtin_amdgcn_s_barrier();
    }
    rs = (rs == 2) ? 0 : rs + 1;
    ss = (ss == 2) ? 0 : ss + 1;
  }

  // C/D layout: col = lane&15, row = (lane>>4)*4 + reg
  const int orow = row0 + wr * 64 + fg * 4;
  const int ocol = col0 + wc * 64 + fr;
#pragma unroll
  for (int mi = 0; mi < 4; ++mi) {
#pragma unroll
    for (int ni = 0; ni < 4; ++ni) {
      const int col = ocol + ni * 16;
      const float bv = bias[col];
#pragma unroll
      for (int rg = 0; rg < 4; ++rg) {
        const size_t idx = (size_t)(orow + mi * 16 + rg) * N + col;
        if (MODE == 0) {
          float v = (float)((i32x4)acc[mi][ni])[rg] + bv;   // exact: |v| < 2^24
          ((unsigned short*)Cout)[idx] = f2bf(v);
        } else {
          float v = ((f32x4)acc[mi][ni])[rg] + bv;
          ((float*)Cout)[idx] = fmaxf(v, 0.f);
        }
      }
    }
  }
}

__global__ __launch_bounds__(256, 3) void gemm_fc1(
    const char* __restrict__ A, const char* __restrict__ Bt,
    const float* __restrict__ bias, void* __restrict__ Cout, int M, int N, int Kb) {
  __shared__ char lds[49152];
  gemm_core<0>(lds, A, Bt, bias, Cout, M, N, Kb);
}

__global__ __launch_bounds__(256, 3) void gemm_fc2(
    const char* __restrict__ A, const char* __restrict__ Bt,
    const float* __restrict__ bias, void* __restrict__ Cout, int M, int N, int Kb) {
  __shared__ char lds[49152];
  gemm_core<1>(lds, A, Bt, bias, Cout, M, N, Kb);
}

// ---------------- launch ----------------

extern "C" void kernel_launch(void* const* d_in, const int* in_sizes, int n_in,
                              void* d_out, int out_size, void* d_ws, size_t ws_size,
                              hipStream_t stream) {
  const float* x  = (const float*)d_in[0];
  const float* w1 = (const float*)d_in[1];
  const float* b1 = (const float*)d_in[2];
  const float* w2 = (const float*)d_in[3];
  const float* b2 = (const float*)d_in[4];
  const float* as = (const float*)d_in[5];

  const int Mrows = 64 * 196;   // 12544
  const int D = 768, H = 3072;

  char* ws = (char*)d_ws;
  size_t off = 0;
  auto align256 = [](size_t v) { return (v + 255) & ~(size_t)255; };
  unsigned* mx = (unsigned*)(ws + off); off += 256;
  char* xq8    = (char*)(ws + off);     off += align256((size_t)Mrows * D);
  char* w1q8   = (char*)(ws + off);     off += align256((size_t)H * D);
  unsigned short* w2q = (unsigned short*)(ws + off); off += align256((size_t)D * H * 2);
  float* b1i = (float*)(ws + off); off += align256((size_t)H * 4);
  float* b2i = (float*)(ws + off); off += align256((size_t)D * 4);
  unsigned short* h = (unsigned short*)(ws + off); off += align256((size_t)Mrows * H * 2);
  if (off > ws_size) return;

  float* out = (float*)d_out;
  float* s_out = out + (out_size - 1);

  hipMemsetAsync(mx, 0, 8, stream);

  const int nw4 = H * D / 4;
  prep_kernel<<<dim3(1024, 3), dim3(256), 0, stream>>>(
      (const float4*)x, (uchar4*)xq8, Mrows * D / 4,
      (const float4*)w1, (const float4*)w2, nw4, mx);
  quantwb_kernel<<<dim3(1024, 3), dim3(256), 0, stream>>>(
      (const float4*)w1, (const float4*)w2, (uchar4*)w1q8, (ushort4*)w2q,
      b1, b2, b1i, b2i, mx, as, s_out, nw4, H, D);

  // fc1: int8, 98x24 = 2352 blocks, Kb = 768
  gemm_fc1<<<dim3((Mrows / 128) * (H / 128)), dim3(256), 0, stream>>>(
      xq8, w1q8, b1i, h, Mrows, H, D);
  // fc2: bf16, 98x6 = 588 blocks, Kb = 6144
  gemm_fc2<<<dim3((Mrows / 128) * (D / 128)), dim3(256), 0, stream>>>(
      (const char*)h, (const char*)w2q, b2i, out, Mrows, D, H * 2);
}

// Round 8
// 153.263 us; speedup vs baseline: 1.0313x; 1.0313x over previous
//
#include <hip/hip_runtime.h>
#include <hip/hip_bf16.h>
#include <type_traits>

typedef __attribute__((ext_vector_type(8))) short bf16x8;
typedef __attribute__((ext_vector_type(4))) float f32x4;
typedef __attribute__((ext_vector_type(4))) int   i32x4;

static __device__ __forceinline__ unsigned short f2bf(float f) {
  union { float f; unsigned u; } cv; cv.f = f;
  unsigned r = cv.u + 0x7fff + ((cv.u >> 16) & 1);   // RNE, no NaNs in this data
  return (unsigned short)(r >> 16);
}

static __device__ __forceinline__ void stage16(const void* g, void* l) {
  __builtin_amdgcn_global_load_lds((const __attribute__((address_space(1))) void*)g,
                                   (__attribute__((address_space(3))) void*)l,
                                   16, 0, 0);
}

// ---------------- prep ----------------
// y==0 (1024 blocks): x f32 -> int8. y==1/2 (96 blocks): maxabs(w1/w2).
__global__ void prep_kernel(const float4* __restrict__ x, uchar4* __restrict__ xq, int n4x,
                            const float4* __restrict__ w1, const float4* __restrict__ w2,
                            int n4w, unsigned* __restrict__ mx) {
  if (blockIdx.y == 0) {
    const int stride = gridDim.x * blockDim.x;
    for (int i = blockIdx.x * blockDim.x + threadIdx.x; i < n4x; i += stride) {
      float4 v = x[i];
      uchar4 o;
      o.x = (unsigned char)(char)fminf(fmaxf(v.x, -127.f), 127.f);
      o.y = (unsigned char)(char)fminf(fmaxf(v.y, -127.f), 127.f);
      o.z = (unsigned char)(char)fminf(fmaxf(v.z, -127.f), 127.f);
      o.w = (unsigned char)(char)fminf(fmaxf(v.w, -127.f), 127.f);
      xq[i] = o;
    }
  } else {
    if (blockIdx.x >= 96) return;
    __shared__ unsigned red[4];
    const float4* w = (blockIdx.y == 1) ? w1 : w2;
    unsigned m = 0;
    const int stride = 96 * 256;
    for (int i = blockIdx.x * blockDim.x + threadIdx.x; i < n4w; i += stride) {
      float4 v = w[i];
      unsigned a;
      a = __float_as_uint(fabsf(v.x)); m = m > a ? m : a;
      a = __float_as_uint(fabsf(v.y)); m = m > a ? m : a;
      a = __float_as_uint(fabsf(v.z)); m = m > a ? m : a;
      a = __float_as_uint(fabsf(v.w)); m = m > a ? m : a;
    }
#pragma unroll
    for (int off = 32; off > 0; off >>= 1) {
      unsigned t = (unsigned)__shfl_down((int)m, off, 64);
      m = m > t ? m : t;
    }
    if ((threadIdx.x & 63) == 0) red[threadIdx.x >> 6] = m;
    __syncthreads();
    if (threadIdx.x == 0) {
      unsigned t0 = red[0] > red[1] ? red[0] : red[1];
      unsigned t1 = red[2] > red[3] ? red[2] : red[3];
      atomicMax(mx + blockIdx.y - 1, t0 > t1 ? t0 : t1);
    }
  }
}

// y==0: w1 -> int8 ; y==1: w2 -> bf16 ; y==2 (block 0): biases + final scale.
__global__ void quantwb_kernel(const float4* __restrict__ w1, const float4* __restrict__ w2,
                               uchar4* __restrict__ w1q, ushort4* __restrict__ w2q,
                               const float* __restrict__ b1, const float* __restrict__ b2,
                               float* __restrict__ b1i, float* __restrict__ b2i,
                               const unsigned* __restrict__ mx, const float* __restrict__ a_s,
                               float* __restrict__ s_out, int n4, int H, int D) {
  const float ws1 = __uint_as_float(mx[0]) / 127.0f;
  const float ws2 = __uint_as_float(mx[1]) / 127.0f;
  const int stride = gridDim.x * blockDim.x;
  if (blockIdx.y == 0) {
    for (int i = blockIdx.x * blockDim.x + threadIdx.x; i < n4; i += stride) {
      float4 v = w1[i];
      uchar4 o;
      o.x = (unsigned char)(char)fminf(fmaxf(rintf(v.x / ws1), -127.f), 127.f);
      o.y = (unsigned char)(char)fminf(fmaxf(rintf(v.y / ws1), -127.f), 127.f);
      o.z = (unsigned char)(char)fminf(fmaxf(rintf(v.z / ws1), -127.f), 127.f);
      o.w = (unsigned char)(char)fminf(fmaxf(rintf(v.w / ws1), -127.f), 127.f);
      w1q[i] = o;
    }
  } else if (blockIdx.y == 1) {
    for (int i = blockIdx.x * blockDim.x + threadIdx.x; i < n4; i += stride) {
      float4 v = w2[i];
      ushort4 o;
      o.x = f2bf(fminf(fmaxf(rintf(v.x / ws2), -127.f), 127.f));
      o.y = f2bf(fminf(fmaxf(rintf(v.y / ws2), -127.f), 127.f));
      o.z = f2bf(fminf(fmaxf(rintf(v.z / ws2), -127.f), 127.f));
      o.w = f2bf(fminf(fmaxf(rintf(v.w / ws2), -127.f), 127.f));
      w2q[i] = o;
    }
  } else {
    if (blockIdx.x != 0) return;
    const float s0 = a_s[0];
    const float s1 = s0 * ws1;
    const float d1 = ws1 * s0;
    const float d2 = ws2 * s1;
    if (threadIdx.x == 0) s_out[0] = s1 * ws2;
    for (int i = threadIdx.x; i < H; i += blockDim.x) {
      float q = rintf(b1[i] / d1);
      b1i[i] = fminf(fmaxf(q, -2147483647.f), 2147483647.f);
    }
    for (int i = threadIdx.x; i < D; i += blockDim.x) {
      float q = rintf(b2[i] / d2);
      b2i[i] = fminf(fmaxf(q, -2147483647.f), 2147483647.f);
    }
  }
}

// ---------------- fc1: 256x256 int8 GEMM, 8 waves, 2-slot BK=128B ----------------
// Per-wave output 128x64 (8x4 frags of 16x16) -> 384 B LDS-read per MFMA.
// Per step (BK=128B = 128 i8 k): reads h0 (12 b128) -> 32 MFMA -> reads h1 ->
// lgkm drain + barrier -> restage current slot (t+2) -> 32 MFMA -> vmcnt(8) -> barrier.
// Swizzle: phys chunk = logical ^ (row&7) on global source + ds_read (0-conflict, R6-proven).

__global__ __launch_bounds__(512, 2) void gemm_fc1(
    const char* __restrict__ A, const char* __restrict__ Bt,
    const float* __restrict__ bias, unsigned short* __restrict__ Cout,
    int M, int N, int Kb)
{
  __shared__ char lds[2 * 65536];
  const int tid = threadIdx.x;
  const int lane = tid & 63;
  const int wave = tid >> 6;
  const int wr = wave >> 2;            // 0..1
  const int wc = wave & 3;             // 0..3

  // 16-row-tile bands, col-major within band (A-band ~3MB stays L2-resident)
  const int nbx = M / 256;             // 49
  const int nby = N / 256;             // 12
  const int bandSize = 16 * nby;
  const int b = blockIdx.x / bandSize;
  const int local = blockIdx.x - b * bandSize;
  const int r0 = b * 16;
  const int rn = min(16, nbx - r0);
  const int c = local / rn;
  const int r = r0 + (local - c * rn);
  const int row0 = r * 256;
  const int col0 = c * 256;

  // staging: segment s = i*512 + tid; row = s>>3 = i*64 + (tid>>3); phys chunk = tid&7
  const int srow = tid >> 3;
  const int chunk = (tid & 7) ^ (srow & 7);
  const char* Ag = A + (size_t)(row0 + srow) * Kb + chunk * 16;
  const char* Bg = Bt + (size_t)(col0 + srow) * Kb + chunk * 16;
  const int wb = wave * 1024;

  auto stage = [&](int slot, int st) {
    char* da = lds + slot * 65536 + wb;
    char* db = lds + slot * 65536 + 32768 + wb;
    const int ko = st << 7;
#pragma unroll
    for (int i = 0; i < 4; ++i)
      stage16(Ag + ko + (size_t)(i * 64) * Kb, da + i * 8192);
#pragma unroll
    for (int i = 0; i < 4; ++i)
      stage16(Bg + ko + (size_t)(i * 64) * Kb, db + i * 8192);
  };

  i32x4 acc[8][4];
#pragma unroll
  for (int i = 0; i < 8; ++i)
#pragma unroll
    for (int j = 0; j < 4; ++j) acc[i][j] = (i32x4)(0);

  const int nS = Kb >> 7;              // 6
  stage(0, 0);
  stage(1, 1);
  asm volatile("s_waitcnt vmcnt(8)" ::: "memory");
  __builtin_amdgcn_s_barrier();

  const int fr = lane & 15;
  const int fg = lane >> 4;
  const int ch0 = ((fg ^ (fr & 7)) & 7) << 4;      // chunk byte offset, h=0 (h=1: ^64)
  const int Abase = (wr * 128 + fr) * 128;
  const int Bbase = 32768 + (wc * 64 + fr) * 128;

  for (int t = 0; t < nS; ++t) {
    const int so = (t & 1) << 16;
    i32x4 af[8], bf[4];
    // ---- half 0 ----
#pragma unroll
    for (int mf = 0; mf < 8; ++mf) af[mf] = *(const i32x4*)(lds + so + Abase + mf * 2048 + ch0);
#pragma unroll
    for (int nf = 0; nf < 4; ++nf) bf[nf] = *(const i32x4*)(lds + so + Bbase + nf * 2048 + ch0);
    __builtin_amdgcn_s_setprio(1);
#pragma unroll
    for (int mf = 0; mf < 8; ++mf)
#pragma unroll
      for (int nf = 0; nf < 4; ++nf)
        acc[mf][nf] = __builtin_amdgcn_mfma_i32_16x16x64_i8(af[mf], bf[nf], acc[mf][nf], 0, 0, 0);
    __builtin_amdgcn_s_setprio(0);
    // ---- half 1 reads ----
#pragma unroll
    for (int mf = 0; mf < 8; ++mf) af[mf] = *(const i32x4*)(lds + so + Abase + mf * 2048 + (ch0 ^ 64));
#pragma unroll
    for (int nf = 0; nf < 4; ++nf) bf[nf] = *(const i32x4*)(lds + so + Bbase + nf * 2048 + (ch0 ^ 64));
    // all waves' reads of this slot complete before restaging it
    asm volatile("s_waitcnt lgkmcnt(0)" ::: "memory");
    __builtin_amdgcn_sched_barrier(0);
    __builtin_amdgcn_s_barrier();
    const bool st = (t + 2 < nS);
    if (st) stage(t & 1, t + 2);
    __builtin_amdgcn_s_setprio(1);
#pragma unroll
    for (int mf = 0; mf < 8; ++mf)
#pragma unroll
      for (int nf = 0; nf < 4; ++nf)
        acc[mf][nf] = __builtin_amdgcn_mfma_i32_16x16x64_i8(af[mf], bf[nf], acc[mf][nf], 0, 0, 0);
    __builtin_amdgcn_s_setprio(0);
    if (t + 1 < nS) {
      if (st) asm volatile("s_waitcnt vmcnt(8)" ::: "memory");
      else    asm volatile("s_waitcnt vmcnt(0)" ::: "memory");
      __builtin_amdgcn_s_barrier();
    }
  }

  // C/D layout: col = lane&15, row = (lane>>4)*4 + reg
  const int orow = row0 + wr * 128 + fg * 4;
  const int ocol = col0 + wc * 64 + fr;
#pragma unroll
  for (int mf = 0; mf < 8; ++mf) {
#pragma unroll
    for (int nf = 0; nf < 4; ++nf) {
      const int col = ocol + nf * 16;
      const float bv = bias[col];
#pragma unroll
      for (int rg = 0; rg < 4; ++rg) {
        float v = (float)acc[mf][nf][rg] + bv;             // exact: |v| < 2^24
        Cout[(size_t)(orow + mf * 16 + rg) * N + col] = f2bf(v);
      }
    }
  }
}

// ---------------- fc2: 128x128 bf16 GEMM (R6 winner config, verbatim) ----------------
// 2-slot BK=128B, lgkm-drain before restage, vmcnt(8), row-major rank + m204.

__global__ __launch_bounds__(256) void gemm_fc2(
    const char* __restrict__ A, const char* __restrict__ Bt,
    const float* __restrict__ bias, float* __restrict__ Cout,
    int M, int N, int Kb)
{
  __shared__ char lds[2 * 32768];
  const int tid = threadIdx.x;
  const int lane = tid & 63;
  const int wave = tid >> 6;
  const int wr = wave >> 1;
  const int wc = wave & 1;

  const int nbx = M / 128;
  const int nby = N / 128;
  const int nwg = nbx * nby;
  const int q8 = nwg >> 3, r8 = nwg & 7;
  const int xcd = blockIdx.x & 7, bidx = blockIdx.x >> 3;
  const int wg = (xcd < r8 ? xcd * (q8 + 1) : r8 * (q8 + 1) + (xcd - r8) * q8) + bidx;
  const int r = wg / nby;              // row-major: same-row tiles adjacent -> same XCD
  const int c = wg % nby;
  const int row0 = r * 128;
  const int col0 = c * 128;

  const int srow = tid >> 3;
  const int chunk = (tid & 7) ^ (srow & 7);
  const char* Ag = A + (size_t)(row0 + srow) * Kb + chunk * 16;
  const char* Bg = Bt + (size_t)(col0 + srow) * Kb + chunk * 16;
  const int stA = wave * 1024;
  const int stB = 16384 + wave * 1024;

  auto stage = [&](int slot, int h) {
    const int hb = h << 7;
    char* da = lds + slot * 32768 + stA;
    char* db = lds + slot * 32768 + stB;
#pragma unroll
    for (int i = 0; i < 4; ++i)
      stage16(Ag + hb + (size_t)(i * 32) * Kb, da + i * 4096);
#pragma unroll
    for (int i = 0; i < 4; ++i)
      stage16(Bg + hb + (size_t)(i * 32) * Kb, db + i * 4096);
  };

  f32x4 acc[4][4];
#pragma unroll
  for (int i = 0; i < 4; ++i)
#pragma unroll
    for (int j = 0; j < 4; ++j) acc[i][j] = (f32x4){0.f, 0.f, 0.f, 0.f};

  const int nS = Kb >> 7;              // 48
  stage(0, 0);
  stage(1, 1);
  asm volatile("s_waitcnt vmcnt(8)" ::: "memory");
  __builtin_amdgcn_s_barrier();

  const int fr = lane & 15;
  const int fg = lane >> 4;
  const int xw = (fg ^ (fr & 7)) << 4;
  const int aoff = (wr * 64 + fr) * 128 + xw;
  const int boff = 16384 + (wc * 64 + fr) * 128 + xw;

  for (int t = 0; t < nS; ++t) {
    const int so = (t & 1) * 32768;
    bf16x8 af[2][4], bf[2][4];
#pragma unroll
    for (int h = 0; h < 2; ++h) {
      const int hx = h << 6;
#pragma unroll
      for (int mi = 0; mi < 4; ++mi)
        af[h][mi] = *(const bf16x8*)(lds + so + ((aoff ^ hx) + mi * 2048));
#pragma unroll
      for (int ni = 0; ni < 4; ++ni)
        bf[h][ni] = *(const bf16x8*)(lds + so + ((boff ^ hx) + ni * 2048));
    }
    asm volatile("s_waitcnt lgkmcnt(0)" ::: "memory");
    __builtin_amdgcn_sched_barrier(0);
    __builtin_amdgcn_s_barrier();
    if (t + 2 < nS) stage(t & 1, t + 2);
    __builtin_amdgcn_s_setprio(1);
#pragma unroll
    for (int h = 0; h < 2; ++h)
#pragma unroll
      for (int mi = 0; mi < 4; ++mi)
#pragma unroll
        for (int ni = 0; ni < 4; ++ni)
          acc[mi][ni] = __builtin_amdgcn_mfma_f32_16x16x32_bf16(
              af[h][mi], bf[h][ni], acc[mi][ni], 0, 0, 0);
    __builtin_amdgcn_s_setprio(0);
    if (t + 2 < nS) asm volatile("s_waitcnt vmcnt(8)" ::: "memory");
    else            asm volatile("s_waitcnt vmcnt(0)" ::: "memory");
    __builtin_amdgcn_s_barrier();
  }

  const int orow = row0 + wr * 64 + fg * 4;
  const int ocol = col0 + wc * 64 + fr;
#pragma unroll
  for (int mi = 0; mi < 4; ++mi) {
#pragma unroll
    for (int ni = 0; ni < 4; ++ni) {
      const int col = ocol + ni * 16;
      const float bv = bias[col];
#pragma unroll
      for (int rg = 0; rg < 4; ++rg) {
        float v = acc[mi][ni][rg] + bv;
        Cout[(size_t)(orow + mi * 16 + rg) * N + col] = fmaxf(v, 0.f);
      }
    }
  }
}

// ---------------- launch ----------------

extern "C" void kernel_launch(void* const* d_in, const int* in_sizes, int n_in,
                              void* d_out, int out_size, void* d_ws, size_t ws_size,
                              hipStream_t stream) {
  const float* x  = (const float*)d_in[0];
  const float* w1 = (const float*)d_in[1];
  const float* b1 = (const float*)d_in[2];
  const float* w2 = (const float*)d_in[3];
  const float* b2 = (const float*)d_in[4];
  const float* as = (const float*)d_in[5];

  const int Mrows = 64 * 196;   // 12544
  const int D = 768, H = 3072;

  char* ws = (char*)d_ws;
  size_t off = 0;
  auto align256 = [](size_t v) { return (v + 255) & ~(size_t)255; };
  unsigned* mx = (unsigned*)(ws + off); off += 256;
  char* xq8    = (char*)(ws + off);     off += align256((size_t)Mrows * D);
  char* w1q8   = (char*)(ws + off);     off += align256((size_t)H * D);
  unsigned short* w2q = (unsigned short*)(ws + off); off += align256((size_t)D * H * 2);
  float* b1i = (float*)(ws + off); off += align256((size_t)H * 4);
  float* b2i = (float*)(ws + off); off += align256((size_t)D * 4);
  unsigned short* h = (unsigned short*)(ws + off); off += align256((size_t)Mrows * H * 2);
  if (off > ws_size) return;

  float* out = (float*)d_out;
  float* s_out = out + (out_size - 1);

  hipMemsetAsync(mx, 0, 8, stream);

  const int nw4 = H * D / 4;
  prep_kernel<<<dim3(1024, 3), dim3(256), 0, stream>>>(
      (const float4*)x, (uchar4*)xq8, Mrows * D / 4,
      (const float4*)w1, (const float4*)w2, nw4, mx);
  quantwb_kernel<<<dim3(1024, 3), dim3(256), 0, stream>>>(
      (const float4*)w1, (const float4*)w2, (uchar4*)w1q8, (ushort4*)w2q,
      b1, b2, b1i, b2i, mx, as, s_out, nw4, H, D);

  // fc1: int8 256x256, 49*12 = 588 blocks, Kb = 768
  gemm_fc1<<<dim3((Mrows / 256) * (H / 256)), dim3(512), 0, stream>>>(
      xq8, w1q8, b1i, h, Mrows, H, D);
  // fc2: bf16 128x128, 98*6 = 588 blocks, Kb = 6144
  gemm_fc2<<<dim3((Mrows / 128) * (D / 128)), dim3(256), 0, stream>>>(
      (const char*)h, (const char*)w2q, b2i, out, Mrows, D, H * 2);
}